// Round 1
// baseline (842.039 us; speedup 1.0000x reference)
//
#include <hip/hip_runtime.h>
#include <math.h>

#define GG 128
#define NPER 512
#define KK 30
#define NN (GG*NPER)        // 65536
#define EE 1048576
#define DNODE 64
#define DIN0 96
#define DL 32
#define TOTAL 97
#define C1C 16
#define C2C 32
#define KW2C 5
#define POOL_LEN 15
#define CONV_OUT 11
#define DENSE 352
#define OUTD 128

// ---------------- edge: e2n = segsum(edge_feat, dst), degcnt = segsum(1, dst) ----------------
__global__ __launch_bounds__(256) void k_edge_init(const float* __restrict__ edge_feat,
                                                   const int* __restrict__ edge_dst,
                                                   float* __restrict__ e2n,
                                                   float* __restrict__ degcnt) {
    int t = blockIdx.x * 256 + threadIdx.x;     // over E*32
    int e = t >> 5, c = t & 31;
    if (e < EE) {
        int d = edge_dst[e];
        atomicAdd(&e2n[d * 32 + c], edge_feat[t]);
        if (c == 0) atomicAdd(&degcnt[d], 1.0f);
    }
}

// ---------------- layer0: y = [node_feat | e2n] @ W0 ; z = y + b0 ----------------
__global__ __launch_bounds__(256) void k_layer0(const float* __restrict__ node_feat,
                                                const float* __restrict__ e2n,
                                                const float* __restrict__ W0,   // 96x32
                                                const float* __restrict__ b0,
                                                float* __restrict__ y, float* __restrict__ z) {
    __shared__ float Wl[DIN0 * DL];
    for (int i = threadIdx.x; i < DIN0 * DL; i += 256) Wl[i] = W0[i];
    __syncthreads();
    int t = blockIdx.x * 256 + threadIdx.x;     // over N*32
    int n = t >> 5, c = t & 31;
    const float* nf = node_feat + n * 64;
    const float* ef = e2n + n * 32;
    float s = 0.f;
    #pragma unroll
    for (int k = 0; k < 64; ++k) s += nf[k] * Wl[k * 32 + c];
    #pragma unroll
    for (int k = 0; k < 32; ++k) s += ef[k] * Wl[(64 + k) * 32 + c];
    y[t] = s;
    z[t] = s + b0[c];
}

// ---------------- scatter: z[dst] += y[src], 32 channels ----------------
__global__ __launch_bounds__(256) void k_scatter32(const int* __restrict__ src,
                                                   const int* __restrict__ dst,
                                                   const float* __restrict__ y,
                                                   float* __restrict__ z) {
    int t = blockIdx.x * 256 + threadIdx.x;     // over E*32
    int e = t >> 5, c = t & 31;
    if (e < EE) {
        int s = src[e], d = dst[e];
        atomicAdd(&z[d * 32 + c], y[s * 32 + c]);
    }
}

__global__ __launch_bounds__(256) void k_scatter1(const int* __restrict__ src,
                                                  const int* __restrict__ dst,
                                                  const float* __restrict__ y,
                                                  float* __restrict__ z) {
    int e = blockIdx.x * 256 + threadIdx.x;
    if (e < EE) atomicAdd(&z[dst[e]], y[src[e]]);
}

// ---------------- mid layers: h = tanh(z_prev/deg) -> hcat ; y = h@W ; z = y + b ----------------
__global__ __launch_bounds__(256) void k_layer(const float* __restrict__ zprev,
                                               const float* __restrict__ degcnt,
                                               const float* __restrict__ W,    // 32x32
                                               const float* __restrict__ b,
                                               float* __restrict__ hcat, int colbase,
                                               float* __restrict__ y, float* __restrict__ z) {
    __shared__ float Wl[DL * DL];
    __shared__ float hb[64 * 33];
    for (int i = threadIdx.x; i < DL * DL; i += 256) Wl[i] = W[i];
    int base = blockIdx.x * 64;
    for (int i = threadIdx.x; i < 64 * 32; i += 256) {
        int nl = i >> 5, c = i & 31;
        int n = base + nl;
        float hv = tanhf(zprev[n * 32 + c] / (degcnt[n] + 1.0f));
        hb[nl * 33 + c] = hv;
        hcat[n * 96 + colbase + c] = hv;
    }
    __syncthreads();
    for (int i = threadIdx.x; i < 64 * 32; i += 256) {
        int nl = i >> 5, c = i & 31;
        int n = base + nl;
        float s = 0.f;
        #pragma unroll
        for (int k = 0; k < 32; ++k) s += hb[nl * 33 + k] * Wl[k * 32 + c];
        y[n * 32 + c] = s;
        z[n * 32 + c] = s + b[c];
    }
}

// ---------------- layer3: h = tanh(z_prev/deg) -> hcat cols 64..95 ; y3 = h@W3 ; z3 = y3 + b3 ----------------
__global__ __launch_bounds__(256) void k_layer3(const float* __restrict__ zprev,
                                                const float* __restrict__ degcnt,
                                                const float* __restrict__ W3,   // 32x1
                                                const float* __restrict__ b3,
                                                float* __restrict__ hcat,
                                                float* __restrict__ y3, float* __restrict__ z3) {
    __shared__ float Wl[32];
    __shared__ float hb[64 * 33];
    if (threadIdx.x < 32) Wl[threadIdx.x] = W3[threadIdx.x];
    int base = blockIdx.x * 64;
    for (int i = threadIdx.x; i < 64 * 32; i += 256) {
        int nl = i >> 5, c = i & 31;
        int n = base + nl;
        float hv = tanhf(zprev[n * 32 + c] / (degcnt[n] + 1.0f));
        hb[nl * 33 + c] = hv;
        hcat[n * 96 + 64 + c] = hv;
    }
    __syncthreads();
    if (threadIdx.x < 64) {
        int nl = threadIdx.x;
        int n = base + nl;
        float s = 0.f;
        #pragma unroll
        for (int k = 0; k < 32; ++k) s += hb[nl * 33 + k] * Wl[k];
        y3[n] = s;
        z3[n] = s + b3[0];
    }
}

// ---------------- head: per-group topk (bitonic, jax tie semantics) + conv stack ----------------
__global__ __launch_bounds__(256) void k_head(const float* __restrict__ z3,
                                              const float* __restrict__ degcnt,
                                              const float* __restrict__ hcat,
                                              const float* __restrict__ cw1, const float* __restrict__ cb1,
                                              const float* __restrict__ cw2, const float* __restrict__ cb2,
                                              const float* __restrict__ ow,  const float* __restrict__ ob,
                                              float* __restrict__ out) {
    __shared__ float sv[NPER];
    __shared__ int   si[NPER];
    __shared__ float pooled[KK][TOTAL];
    __shared__ float c1b[C1C][KK];
    __shared__ float p1[C1C][POOL_LEN];
    __shared__ float flat[DENSE];
    int g = blockIdx.x;
    int tid = threadIdx.x;

    for (int i = tid; i < NPER; i += 256) {
        int n = g * NPER + i;
        sv[i] = tanhf(z3[n] / (degcnt[n] + 1.0f));
        si[i] = i;
    }
    __syncthreads();

    // bitonic sort: descending by value, ties -> ascending index (matches jax.lax.top_k)
    for (int ksz = 2; ksz <= NPER; ksz <<= 1) {
        for (int j = ksz >> 1; j > 0; j >>= 1) {
            for (int i = tid; i < NPER; i += 256) {
                int ixj = i ^ j;
                if (ixj > i) {
                    float vi = sv[i], vj = sv[ixj];
                    int ii = si[i], ij = si[ixj];
                    bool b_ji = (vj > vi) || (vj == vi && ij < ii); // elem[ixj] ranks before elem[i]
                    bool up = ((i & ksz) == 0);
                    if (up ? b_ji : !b_ji) {
                        sv[i] = vj; sv[ixj] = vi;
                        si[i] = ij; si[ixj] = ii;
                    }
                }
            }
            __syncthreads();
        }
    }

    // gather pooled (K x 97); channel 96 is the (sorted) sort value itself
    for (int t = tid; t < KK * TOTAL; t += 256) {
        int k = t / TOTAL, d = t - k * TOTAL;
        if (d < 96) {
            int n = g * NPER + si[k];
            pooled[k][d] = hcat[n * 96 + d];
        } else {
            pooled[k][96] = sv[k];
        }
    }
    __syncthreads();

    // c1[o][k] = relu(cw1[o,:] . pooled[k,:] + cb1[o])
    for (int t = tid; t < C1C * KK; t += 256) {
        int o = t / KK, k = t - o * KK;
        float s = cb1[o];
        for (int d = 0; d < TOTAL; ++d) s += cw1[o * TOTAL + d] * pooled[k][d];
        c1b[o][k] = fmaxf(s, 0.f);
    }
    __syncthreads();

    // maxpool pairs -> p1 (16 x 15)
    for (int t = tid; t < C1C * POOL_LEN; t += 256) {
        int o = t / POOL_LEN, x = t - o * POOL_LEN;
        p1[o][x] = fmaxf(c1b[o][2 * x], c1b[o][2 * x + 1]);
    }
    __syncthreads();

    // conv1d VALID -> (32 x 11), relu, flatten
    for (int t = tid; t < C2C * CONV_OUT; t += 256) {
        int o = t / CONV_OUT, x = t - o * CONV_OUT;
        float s = cb2[o];
        for (int i = 0; i < C1C; ++i) {
            #pragma unroll
            for (int j = 0; j < KW2C; ++j)
                s += cw2[(o * C1C + i) * KW2C + j] * p1[i][x + j];
        }
        flat[o * CONV_OUT + x] = fmaxf(s, 0.f);
    }
    __syncthreads();

    // dense: out[g][m] = relu(flat . ow[:,m] + ob[m])
    for (int m = tid; m < OUTD; m += 256) {
        float s = ob[m];
        for (int d = 0; d < DENSE; ++d) s += flat[d] * ow[d * OUTD + m];
        out[g * OUTD + m] = fmaxf(s, 0.f);
    }
}

extern "C" void kernel_launch(void* const* d_in, const int* in_sizes, int n_in,
                              void* d_out, int out_size, void* d_ws, size_t ws_size,
                              hipStream_t stream) {
    const float* node_feat = (const float*)d_in[0];
    const float* edge_feat = (const float*)d_in[1];
    const int*   edge_src  = (const int*)  d_in[2];
    const int*   edge_dst  = (const int*)  d_in[3];
    const float* W0 = (const float*)d_in[4];
    const float* b0 = (const float*)d_in[5];
    const float* W1 = (const float*)d_in[6];
    const float* b1 = (const float*)d_in[7];
    const float* W2 = (const float*)d_in[8];
    const float* b2 = (const float*)d_in[9];
    const float* W3 = (const float*)d_in[10];
    const float* b3 = (const float*)d_in[11];
    const float* cw1 = (const float*)d_in[12];
    const float* cb1 = (const float*)d_in[13];
    const float* cw2 = (const float*)d_in[14];
    const float* cb2 = (const float*)d_in[15];
    const float* ow  = (const float*)d_in[16];
    const float* ob  = (const float*)d_in[17];
    float* outp = (float*)d_out;

    float* ws     = (float*)d_ws;
    float* e2n    = ws;                 // N*32
    float* degcnt = e2n + NN * 32;      // N   (contiguous with e2n for one memset)
    float* y      = degcnt + NN;        // N*32
    float* z      = y + NN * 32;        // N*32
    float* y3     = z + NN * 32;        // N
    float* z3v    = y3 + NN;            // N
    float* hcat   = z3v + NN;           // N*96

    hipMemsetAsync(e2n, 0, (size_t)(NN * 32 + NN) * sizeof(float), stream);

    k_edge_init<<<EE * 32 / 256, 256, 0, stream>>>(edge_feat, edge_dst, e2n, degcnt);

    // layer 0
    k_layer0<<<NN * 32 / 256, 256, 0, stream>>>(node_feat, e2n, W0, b0, y, z);
    k_scatter32<<<EE * 32 / 256, 256, 0, stream>>>(edge_src, edge_dst, y, z);
    // layer 1 (h1 -> hcat cols 0..31)
    k_layer<<<NN / 64, 256, 0, stream>>>(z, degcnt, W1, b1, hcat, 0, y, z);
    k_scatter32<<<EE * 32 / 256, 256, 0, stream>>>(edge_src, edge_dst, y, z);
    // layer 2 (h2 -> hcat cols 32..63)
    k_layer<<<NN / 64, 256, 0, stream>>>(z, degcnt, W2, b2, hcat, 32, y, z);
    k_scatter32<<<EE * 32 / 256, 256, 0, stream>>>(edge_src, edge_dst, y, z);
    // layer 3 (h3 -> hcat cols 64..95; scalar y3/z3)
    k_layer3<<<NN / 64, 256, 0, stream>>>(z, degcnt, W3, b3, hcat, y3, z3v);
    k_scatter1<<<EE / 256, 256, 0, stream>>>(edge_src, edge_dst, y3, z3v);

    // head
    k_head<<<GG, 256, 0, stream>>>(z3v, degcnt, hcat, cw1, cb1, cw2, cb2, ow, ob, outp);
}

// Round 2
// 613.658 us; speedup vs baseline: 1.3722x; 1.3722x over previous
//
#include <hip/hip_runtime.h>
#include <math.h>

#define GG 128
#define NPER 512
#define KK 30
#define NN (GG*NPER)        // 65536
#define EE 1048576
#define DNODE 64
#define DIN0 96
#define DL 32
#define TOTAL 97
#define C1C 16
#define C2C 32
#define KW2C 5
#define POOL_LEN 15
#define CONV_OUT 11
#define DENSE 352
#define OUTD 128

// ================= CSR build =================
__global__ __launch_bounds__(256) void k_count(const int* __restrict__ dst, int* __restrict__ cnt) {
    int e = blockIdx.x * 256 + threadIdx.x;
    if (e < EE) atomicAdd(&cnt[dst[e]], 1);
}

// single block, 1024 threads: exclusive scan of cnt[N] -> rowptr, cursor; degf = cnt+1
__global__ __launch_bounds__(1024) void k_scan(const int* __restrict__ cnt,
                                               int* __restrict__ rowptr,
                                               int* __restrict__ cursor,
                                               float* __restrict__ degf) {
    __shared__ int sbuf[2][1024];
    int t = threadIdx.x;
    int base = t * 64;
    int s = 0;
    for (int i = 0; i < 64; ++i) s += cnt[base + i];
    sbuf[0][t] = s;
    __syncthreads();
    int cur = 0;
    for (int off = 1; off < 1024; off <<= 1) {
        int v = sbuf[cur][t];
        if (t >= off) v += sbuf[cur][t - off];
        sbuf[cur ^ 1][t] = v;
        __syncthreads();
        cur ^= 1;
    }
    int run = sbuf[cur][t] - s;   // exclusive prefix of this thread's chunk
    for (int i = 0; i < 64; ++i) {
        int c = cnt[base + i];
        rowptr[base + i] = run;
        cursor[base + i] = run;
        degf[base + i]   = (float)c + 1.0f;
        run += c;
    }
    if (t == 1023) rowptr[NN] = run;   // == EE
}

__global__ __launch_bounds__(256) void k_fill(const int* __restrict__ src,
                                              const int* __restrict__ dst,
                                              int* __restrict__ cursor,
                                              int* __restrict__ s_src,
                                              int* __restrict__ s_eid) {
    int e = blockIdx.x * 256 + threadIdx.x;
    if (e < EE) {
        int d = dst[e];
        int pos = atomicAdd(&cursor[d], 1);
        s_src[pos] = src[e];
        s_eid[pos] = e;
    }
}

// ================= e2n gather: e2n[n] = sum edge_feat[eid] over incoming =================
__global__ __launch_bounds__(256) void k_e2n(const float* __restrict__ edge_feat,
                                             const int* __restrict__ rowptr,
                                             const int* __restrict__ s_eid,
                                             float* __restrict__ e2n) {
    int t = blockIdx.x * 256 + threadIdx.x;   // over N*8
    int n = t >> 3, l = t & 7;
    int beg = rowptr[n], end = rowptr[n + 1];
    const float4* ef4 = (const float4*)edge_feat;
    float4 s = make_float4(0.f, 0.f, 0.f, 0.f);
    for (int j = beg; j < end; ++j) {
        int e = s_eid[j];
        float4 v = ef4[e * 8 + l];
        s.x += v.x; s.y += v.y; s.z += v.z; s.w += v.w;
    }
    ((float4*)e2n)[n * 8 + l] = s;
}

// ================= layer0: y = [node_feat | e2n] @ W0 =================
__global__ __launch_bounds__(256) void k_layer0(const float* __restrict__ node_feat,
                                                const float* __restrict__ e2n,
                                                const float* __restrict__ W0,   // 96x32
                                                float* __restrict__ y) {
    __shared__ float Wl[DIN0 * DL];
    for (int i = threadIdx.x; i < DIN0 * DL; i += 256) Wl[i] = W0[i];
    __syncthreads();
    int t = blockIdx.x * 256 + threadIdx.x;     // over N*32
    int n = t >> 5, c = t & 31;
    const float* nf = node_feat + n * 64;
    const float* ef = e2n + n * 32;
    float s = 0.f;
    #pragma unroll
    for (int k = 0; k < 64; ++k) s += nf[k] * Wl[k * 32 + c];
    #pragma unroll
    for (int k = 0; k < 32; ++k) s += ef[k] * Wl[(64 + k) * 32 + c];
    y[t] = s;
}

// ================= gather round: z[n] = y[n] + b + sum_{src in-edges} y[src] =================
__global__ __launch_bounds__(256) void k_gather32(const int* __restrict__ rowptr,
                                                  const int* __restrict__ s_src,
                                                  const float* __restrict__ y,
                                                  const float* __restrict__ b,
                                                  float* __restrict__ z) {
    int t = blockIdx.x * 256 + threadIdx.x;   // over N*8
    int n = t >> 3, l = t & 7;
    int beg = rowptr[n], end = rowptr[n + 1];
    const float4* y4 = (const float4*)y;
    float4 bb = ((const float4*)b)[l];
    float4 s = y4[n * 8 + l];
    s.x += bb.x; s.y += bb.y; s.z += bb.z; s.w += bb.w;
    for (int j = beg; j < end; ++j) {
        int sp = s_src[j];
        float4 v = y4[sp * 8 + l];
        s.x += v.x; s.y += v.y; s.z += v.z; s.w += v.w;
    }
    ((float4*)z)[n * 8 + l] = s;
}

__global__ __launch_bounds__(256) void k_gather1(const int* __restrict__ rowptr,
                                                 const int* __restrict__ s_src,
                                                 const float* __restrict__ y3,
                                                 const float* __restrict__ b3,
                                                 float* __restrict__ z3) {
    int n = blockIdx.x * 256 + threadIdx.x;
    if (n < NN) {
        int beg = rowptr[n], end = rowptr[n + 1];
        float s = y3[n] + b3[0];
        for (int j = beg; j < end; ++j) s += y3[s_src[j]];
        z3[n] = s;
    }
}

// ================= mid layers: h = tanh(z/deg) -> hcat ; y = h@W =================
__global__ __launch_bounds__(256) void k_layer(const float* __restrict__ z,
                                               const float* __restrict__ degf,
                                               const float* __restrict__ W,    // 32x32
                                               float* __restrict__ hcat, int colbase,
                                               float* __restrict__ y) {
    __shared__ float Wl[DL * DL];
    __shared__ float hb[64 * 33];
    for (int i = threadIdx.x; i < DL * DL; i += 256) Wl[i] = W[i];
    int base = blockIdx.x * 64;
    for (int i = threadIdx.x; i < 64 * 32; i += 256) {
        int nl = i >> 5, c = i & 31;
        int n = base + nl;
        float hv = tanhf(z[n * 32 + c] / degf[n]);
        hb[nl * 33 + c] = hv;
        hcat[n * 96 + colbase + c] = hv;
    }
    __syncthreads();
    for (int i = threadIdx.x; i < 64 * 32; i += 256) {
        int nl = i >> 5, c = i & 31;
        int n = base + nl;
        float s = 0.f;
        #pragma unroll
        for (int k = 0; k < 32; ++k) s += hb[nl * 33 + k] * Wl[k * 32 + c];
        y[n * 32 + c] = s;
    }
}

// ================= layer3: h -> hcat cols 64..95 ; y3 = h@W3 =================
__global__ __launch_bounds__(256) void k_layer3(const float* __restrict__ z,
                                                const float* __restrict__ degf,
                                                const float* __restrict__ W3,   // 32x1
                                                float* __restrict__ hcat,
                                                float* __restrict__ y3) {
    __shared__ float Wl[32];
    __shared__ float hb[64 * 33];
    if (threadIdx.x < 32) Wl[threadIdx.x] = W3[threadIdx.x];
    int base = blockIdx.x * 64;
    for (int i = threadIdx.x; i < 64 * 32; i += 256) {
        int nl = i >> 5, c = i & 31;
        int n = base + nl;
        float hv = tanhf(z[n * 32 + c] / degf[n]);
        hb[nl * 33 + c] = hv;
        hcat[n * 96 + 64 + c] = hv;
    }
    __syncthreads();
    if (threadIdx.x < 64) {
        int nl = threadIdx.x;
        int n = base + nl;
        float s = 0.f;
        #pragma unroll
        for (int k = 0; k < 32; ++k) s += hb[nl * 33 + k] * Wl[k];
        y3[n] = s;
    }
}

// ================= head: per-group topk (bitonic, jax tie semantics) + conv stack =================
__global__ __launch_bounds__(256) void k_head(const float* __restrict__ z3,
                                              const float* __restrict__ degf,
                                              const float* __restrict__ hcat,
                                              const float* __restrict__ cw1, const float* __restrict__ cb1,
                                              const float* __restrict__ cw2, const float* __restrict__ cb2,
                                              const float* __restrict__ ow,  const float* __restrict__ ob,
                                              float* __restrict__ out) {
    __shared__ float sv[NPER];
    __shared__ int   si[NPER];
    __shared__ float pooled[KK][TOTAL];
    __shared__ float c1b[C1C][KK];
    __shared__ float p1[C1C][POOL_LEN];
    __shared__ float flat[DENSE];
    int g = blockIdx.x;
    int tid = threadIdx.x;

    for (int i = tid; i < NPER; i += 256) {
        int n = g * NPER + i;
        sv[i] = tanhf(z3[n] / degf[n]);
        si[i] = i;
    }
    __syncthreads();

    // bitonic sort: descending by value, ties -> ascending index (matches jax.lax.top_k)
    for (int ksz = 2; ksz <= NPER; ksz <<= 1) {
        for (int j = ksz >> 1; j > 0; j >>= 1) {
            for (int i = tid; i < NPER; i += 256) {
                int ixj = i ^ j;
                if (ixj > i) {
                    float vi = sv[i], vj = sv[ixj];
                    int ii = si[i], ij = si[ixj];
                    bool b_ji = (vj > vi) || (vj == vi && ij < ii);
                    bool up = ((i & ksz) == 0);
                    if (up ? b_ji : !b_ji) {
                        sv[i] = vj; sv[ixj] = vi;
                        si[i] = ij; si[ixj] = ii;
                    }
                }
            }
            __syncthreads();
        }
    }

    for (int t = tid; t < KK * TOTAL; t += 256) {
        int k = t / TOTAL, d = t - k * TOTAL;
        if (d < 96) {
            int n = g * NPER + si[k];
            pooled[k][d] = hcat[n * 96 + d];
        } else {
            pooled[k][96] = sv[k];
        }
    }
    __syncthreads();

    for (int t = tid; t < C1C * KK; t += 256) {
        int o = t / KK, k = t - o * KK;
        float s = cb1[o];
        for (int d = 0; d < TOTAL; ++d) s += cw1[o * TOTAL + d] * pooled[k][d];
        c1b[o][k] = fmaxf(s, 0.f);
    }
    __syncthreads();

    for (int t = tid; t < C1C * POOL_LEN; t += 256) {
        int o = t / POOL_LEN, x = t - o * POOL_LEN;
        p1[o][x] = fmaxf(c1b[o][2 * x], c1b[o][2 * x + 1]);
    }
    __syncthreads();

    for (int t = tid; t < C2C * CONV_OUT; t += 256) {
        int o = t / CONV_OUT, x = t - o * CONV_OUT;
        float s = cb2[o];
        for (int i = 0; i < C1C; ++i) {
            #pragma unroll
            for (int j = 0; j < KW2C; ++j)
                s += cw2[(o * C1C + i) * KW2C + j] * p1[i][x + j];
        }
        flat[o * CONV_OUT + x] = fmaxf(s, 0.f);
    }
    __syncthreads();

    for (int m = tid; m < OUTD; m += 256) {
        float s = ob[m];
        for (int d = 0; d < DENSE; ++d) s += flat[d] * ow[d * OUTD + m];
        out[g * OUTD + m] = fmaxf(s, 0.f);
    }
}

extern "C" void kernel_launch(void* const* d_in, const int* in_sizes, int n_in,
                              void* d_out, int out_size, void* d_ws, size_t ws_size,
                              hipStream_t stream) {
    const float* node_feat = (const float*)d_in[0];
    const float* edge_feat = (const float*)d_in[1];
    const int*   edge_src  = (const int*)  d_in[2];
    const int*   edge_dst  = (const int*)  d_in[3];
    const float* W0 = (const float*)d_in[4];
    const float* b0 = (const float*)d_in[5];
    const float* W1 = (const float*)d_in[6];
    const float* b1 = (const float*)d_in[7];
    const float* W2 = (const float*)d_in[8];
    const float* b2 = (const float*)d_in[9];
    const float* W3 = (const float*)d_in[10];
    const float* b3 = (const float*)d_in[11];
    const float* cw1 = (const float*)d_in[12];
    const float* cb1 = (const float*)d_in[13];
    const float* cw2 = (const float*)d_in[14];
    const float* cb2 = (const float*)d_in[15];
    const float* ow  = (const float*)d_in[16];
    const float* ob  = (const float*)d_in[17];
    float* outp = (float*)d_out;

    // ---- workspace layout ----
    float* ws   = (float*)d_ws;
    float* y    = ws;                   // N*32
    float* z    = y + NN * 32;          // N*32   (also aliased as e2n: consumed by layer0 before gather overwrites)
    float* y3   = z + NN * 32;          // N
    float* z3v  = y3 + NN;              // N
    float* degf = z3v + NN;             // N
    float* hcat = degf + NN;            // N*96
    int* cnt    = (int*)(hcat + (size_t)NN * 96);  // N
    int* rowptr = cnt + NN;             // N+1
    int* cursor = rowptr + NN + 1;      // N
    int* s_src  = cursor + NN;          // E
    int* s_eid  = s_src + EE;           // E
    float* e2n  = z;                    // alias

    hipMemsetAsync(cnt, 0, (size_t)NN * sizeof(int), stream);

    // CSR build
    k_count<<<EE / 256, 256, 0, stream>>>(edge_dst, cnt);
    k_scan<<<1, 1024, 0, stream>>>(cnt, rowptr, cursor, degf);
    k_fill<<<EE / 256, 256, 0, stream>>>(edge_src, edge_dst, cursor, s_src, s_eid);

    // e2n gather + layer0
    k_e2n<<<NN * 8 / 256, 256, 0, stream>>>(edge_feat, rowptr, s_eid, e2n);
    k_layer0<<<NN * 32 / 256, 256, 0, stream>>>(node_feat, e2n, W0, y);
    k_gather32<<<NN * 8 / 256, 256, 0, stream>>>(rowptr, s_src, y, b0, z);

    k_layer<<<NN / 64, 256, 0, stream>>>(z, degf, W1, hcat, 0, y);
    k_gather32<<<NN * 8 / 256, 256, 0, stream>>>(rowptr, s_src, y, b1, z);

    k_layer<<<NN / 64, 256, 0, stream>>>(z, degf, W2, hcat, 32, y);
    k_gather32<<<NN * 8 / 256, 256, 0, stream>>>(rowptr, s_src, y, b2, z);

    k_layer3<<<NN / 64, 256, 0, stream>>>(z, degf, W3, hcat, y3);
    k_gather1<<<NN / 256, 256, 0, stream>>>(rowptr, s_src, y3, b3, z3v);

    k_head<<<GG, 256, 0, stream>>>(z3v, degf, hcat, cw1, cb1, cw2, cb2, ow, ob, outp);
}

// Round 3
// 490.533 us; speedup vs baseline: 1.7166x; 1.2510x over previous
//
#include <hip/hip_runtime.h>
#include <math.h>

#define GG 128
#define NPER 512
#define KK 30
#define NN (GG*NPER)        // 65536
#define EE 1048576
#define DIN0 96
#define DL 32
#define TOTAL 97
#define C1C 16
#define C2C 32
#define KW2C 5
#define POOL_LEN 15
#define CONV_OUT 11
#define DENSE 352
#define OUTD 128
#define PB_CAP 6144         // per-bucket LDS staging capacity (mean 4096, sd 64)

typedef unsigned long long u64;

// ================= P0: coarse bucket histogram (bucket = dst>>8) =================
__global__ __launch_bounds__(256) void k_bhist(const int* __restrict__ dst, int* __restrict__ bhist) {
    __shared__ int h[256];
    int t = threadIdx.x;
    h[t] = 0;
    __syncthreads();
    int base = blockIdx.x * 4096;
    for (int i = t; i < 4096; i += 256) atomicAdd(&h[dst[base + i] >> 8], 1);
    __syncthreads();
    atomicAdd(&bhist[t], h[t]);
}

// ================= P0b: scan 256 bucket totals -> bbase[257], bcur =================
__global__ __launch_bounds__(256) void k_bscan(const int* __restrict__ bhist,
                                               int* __restrict__ bbase, int* __restrict__ bcur) {
    __shared__ int sc[2][256];
    int t = threadIdx.x;
    int v0 = bhist[t];
    sc[0][t] = v0;
    __syncthreads();
    int c = 0;
    for (int off = 1; off < 256; off <<= 1) {
        int v = sc[c][t];
        if (t >= off) v += sc[c][t - off];
        sc[c ^ 1][t] = v;
        __syncthreads();
        c ^= 1;
    }
    int incl = sc[c][t];
    bbase[t] = incl - v0;
    bcur[t]  = incl - v0;
    if (t == 255) bbase[256] = incl;   // == EE
}

// ================= PA: LDS-staged bucket scatter, run-coalesced flush =================
// packed: bkt(8b)<<44 | eid(20b)<<24 | src(16b)<<8 | dstloc(8b)
__global__ __launch_bounds__(256) void k_bucket(const int* __restrict__ src, const int* __restrict__ dst,
                                                int* __restrict__ bcur, u64* __restrict__ bedges) {
    __shared__ u64 stage[4096];
    __shared__ int hist[256], sc[2][256], excl[256], cur[256], runbase[256];
    int t = threadIdx.x;
    hist[t] = 0; cur[t] = 0;
    __syncthreads();
    int base = blockIdx.x * 4096;
    u64 r[16];
    #pragma unroll
    for (int i = 0; i < 16; ++i) {
        int e = base + t + i * 256;
        int d = dst[e], s = src[e];
        int bkt = d >> 8;
        r[i] = ((u64)bkt << 44) | ((u64)e << 24) | ((u64)s << 8) | (u64)(d & 255);
        atomicAdd(&hist[bkt], 1);
    }
    __syncthreads();
    sc[0][t] = hist[t];
    __syncthreads();
    int c = 0;
    for (int off = 1; off < 256; off <<= 1) {
        int v = sc[c][t];
        if (t >= off) v += sc[c][t - off];
        sc[c ^ 1][t] = v;
        __syncthreads();
        c ^= 1;
    }
    excl[t] = sc[c][t] - hist[t];
    runbase[t] = atomicAdd(&bcur[t], hist[t]);
    __syncthreads();
    #pragma unroll
    for (int i = 0; i < 16; ++i) {
        int bkt = (int)(r[i] >> 44);
        int li = excl[bkt] + atomicAdd(&cur[bkt], 1);
        stage[li] = r[i];
    }
    __syncthreads();
    for (int idx = t; idx < 4096; idx += 256) {
        u64 p = stage[idx];
        int bkt = (int)(p >> 44);
        bedges[runbase[bkt] + (idx - excl[bkt])] = p;
    }
}

// ================= PB: per-bucket local CSR (rowptr, degf, s_src, s_eid) =================
__global__ __launch_bounds__(256) void k_csr(const u64* __restrict__ bedges, const int* __restrict__ bbase,
                                             int* __restrict__ rowptr, float* __restrict__ degf,
                                             int* __restrict__ s_src, int* __restrict__ s_eid) {
    __shared__ u64 stage[PB_CAP];
    __shared__ int hist[256], sc[2][256], excl[256], cur[256];
    int t = threadIdx.x, b = blockIdx.x;
    hist[t] = 0; cur[t] = 0;
    __syncthreads();
    int beg = bbase[b], end = bbase[b + 1];
    int cnt = end - beg;
    for (int j = t; j < cnt; j += 256) {
        u64 p = bedges[beg + j];
        if (j < PB_CAP) stage[j] = p;
        atomicAdd(&hist[(int)(p & 255)], 1);
    }
    __syncthreads();
    sc[0][t] = hist[t];
    __syncthreads();
    int c = 0;
    for (int off = 1; off < 256; off <<= 1) {
        int v = sc[c][t];
        if (t >= off) v += sc[c][t - off];
        sc[c ^ 1][t] = v;
        __syncthreads();
        c ^= 1;
    }
    excl[t] = sc[c][t] - hist[t];
    int n = b * 256 + t;
    rowptr[n] = beg + excl[t];
    degf[n] = (float)hist[t] + 1.0f;
    if (b == 255 && t == 255) rowptr[NN] = EE;
    __syncthreads();
    int lim = cnt < PB_CAP ? cnt : PB_CAP;
    for (int j = t; j < lim; j += 256) {
        u64 p = stage[j];
        int dl = (int)(p & 255);
        int pos = beg + excl[dl] + atomicAdd(&cur[dl], 1);
        s_src[pos] = (int)((p >> 8) & 0xFFFF);
        s_eid[pos] = (int)((p >> 24) & 0xFFFFF);
    }
    for (int j = PB_CAP + t; j < cnt; j += 256) {   // overflow guard (practically never)
        u64 p = bedges[beg + j];
        int dl = (int)(p & 255);
        int pos = beg + excl[dl] + atomicAdd(&cur[dl], 1);
        s_src[pos] = (int)((p >> 8) & 0xFFFF);
        s_eid[pos] = (int)((p >> 24) & 0xFFFFF);
    }
}

// ================= e2n gather =================
__global__ __launch_bounds__(256) void k_e2n(const float* __restrict__ edge_feat,
                                             const int* __restrict__ rowptr,
                                             const int* __restrict__ s_eid,
                                             float* __restrict__ e2n) {
    int t = blockIdx.x * 256 + threadIdx.x;   // over N*8
    int n = t >> 3, l = t & 7;
    int beg = rowptr[n], end = rowptr[n + 1];
    const float4* ef4 = (const float4*)edge_feat;
    float4 s = make_float4(0.f, 0.f, 0.f, 0.f);
    for (int j = beg; j < end; ++j) {
        int e = s_eid[j];
        float4 v = ef4[e * 8 + l];
        s.x += v.x; s.y += v.y; s.z += v.z; s.w += v.w;
    }
    ((float4*)e2n)[n * 8 + l] = s;
}

// ================= layer0: y = [node_feat | e2n] @ W0 =================
__global__ __launch_bounds__(256) void k_layer0(const float* __restrict__ node_feat,
                                                const float* __restrict__ e2n,
                                                const float* __restrict__ W0,
                                                float* __restrict__ y) {
    __shared__ float Wl[DIN0 * DL];
    for (int i = threadIdx.x; i < DIN0 * DL; i += 256) Wl[i] = W0[i];
    __syncthreads();
    int t = blockIdx.x * 256 + threadIdx.x;
    int n = t >> 5, c = t & 31;
    const float* nf = node_feat + n * 64;
    const float* ef = e2n + n * 32;
    float s = 0.f;
    #pragma unroll
    for (int k = 0; k < 64; ++k) s += nf[k] * Wl[k * 32 + c];
    #pragma unroll
    for (int k = 0; k < 32; ++k) s += ef[k] * Wl[(64 + k) * 32 + c];
    y[t] = s;
}

// ================= gather round =================
__global__ __launch_bounds__(256) void k_gather32(const int* __restrict__ rowptr,
                                                  const int* __restrict__ s_src,
                                                  const float* __restrict__ y,
                                                  const float* __restrict__ b,
                                                  float* __restrict__ z) {
    int t = blockIdx.x * 256 + threadIdx.x;
    int n = t >> 3, l = t & 7;
    int beg = rowptr[n], end = rowptr[n + 1];
    const float4* y4 = (const float4*)y;
    float4 bb = ((const float4*)b)[l];
    float4 s = y4[n * 8 + l];
    s.x += bb.x; s.y += bb.y; s.z += bb.z; s.w += bb.w;
    for (int j = beg; j < end; ++j) {
        int sp = s_src[j];
        float4 v = y4[sp * 8 + l];
        s.x += v.x; s.y += v.y; s.z += v.z; s.w += v.w;
    }
    ((float4*)z)[n * 8 + l] = s;
}

__global__ __launch_bounds__(256) void k_gather1(const int* __restrict__ rowptr,
                                                 const int* __restrict__ s_src,
                                                 const float* __restrict__ y3,
                                                 const float* __restrict__ b3,
                                                 float* __restrict__ z3) {
    int n = blockIdx.x * 256 + threadIdx.x;
    if (n < NN) {
        int beg = rowptr[n], end = rowptr[n + 1];
        float s = y3[n] + b3[0];
        for (int j = beg; j < end; ++j) s += y3[s_src[j]];
        z3[n] = s;
    }
}

// ================= mid layers =================
__global__ __launch_bounds__(256) void k_layer(const float* __restrict__ z,
                                               const float* __restrict__ degf,
                                               const float* __restrict__ W,
                                               float* __restrict__ hcat, int colbase,
                                               float* __restrict__ y) {
    __shared__ float Wl[DL * DL];
    __shared__ float hb[64 * 33];
    for (int i = threadIdx.x; i < DL * DL; i += 256) Wl[i] = W[i];
    int base = blockIdx.x * 64;
    for (int i = threadIdx.x; i < 64 * 32; i += 256) {
        int nl = i >> 5, c = i & 31;
        int n = base + nl;
        float hv = tanhf(z[n * 32 + c] / degf[n]);
        hb[nl * 33 + c] = hv;
        hcat[n * 96 + colbase + c] = hv;
    }
    __syncthreads();
    for (int i = threadIdx.x; i < 64 * 32; i += 256) {
        int nl = i >> 5, c = i & 31;
        int n = base + nl;
        float s = 0.f;
        #pragma unroll
        for (int k = 0; k < 32; ++k) s += hb[nl * 33 + k] * Wl[k * 32 + c];
        y[n * 32 + c] = s;
    }
}

__global__ __launch_bounds__(256) void k_layer3(const float* __restrict__ z,
                                                const float* __restrict__ degf,
                                                const float* __restrict__ W3,
                                                float* __restrict__ hcat,
                                                float* __restrict__ y3) {
    __shared__ float Wl[32];
    __shared__ float hb[64 * 33];
    if (threadIdx.x < 32) Wl[threadIdx.x] = W3[threadIdx.x];
    int base = blockIdx.x * 64;
    for (int i = threadIdx.x; i < 64 * 32; i += 256) {
        int nl = i >> 5, c = i & 31;
        int n = base + nl;
        float hv = tanhf(z[n * 32 + c] / degf[n]);
        hb[nl * 33 + c] = hv;
        hcat[n * 96 + 64 + c] = hv;
    }
    __syncthreads();
    if (threadIdx.x < 64) {
        int nl = threadIdx.x;
        int n = base + nl;
        float s = 0.f;
        #pragma unroll
        for (int k = 0; k < 32; ++k) s += hb[nl * 33 + k] * Wl[k];
        y3[n] = s;
    }
}

// ================= head (512 threads: one per sort element) =================
__global__ __launch_bounds__(512) void k_head(const float* __restrict__ z3,
                                              const float* __restrict__ degf,
                                              const float* __restrict__ hcat,
                                              const float* __restrict__ cw1, const float* __restrict__ cb1,
                                              const float* __restrict__ cw2, const float* __restrict__ cb2,
                                              const float* __restrict__ ow,  const float* __restrict__ ob,
                                              float* __restrict__ out) {
    __shared__ float sv[NPER];
    __shared__ int   si[NPER];
    __shared__ float pooled[KK][TOTAL];
    __shared__ float c1b[C1C][KK];
    __shared__ float p1[C1C][POOL_LEN];
    __shared__ float flat[DENSE];
    int g = blockIdx.x;
    int tid = threadIdx.x;

    {
        int n = g * NPER + tid;
        sv[tid] = tanhf(z3[n] / degf[n]);
        si[tid] = tid;
    }
    __syncthreads();

    // bitonic sort: descending by value, ties -> ascending index (jax.lax.top_k semantics)
    for (int ksz = 2; ksz <= NPER; ksz <<= 1) {
        for (int j = ksz >> 1; j > 0; j >>= 1) {
            int i = tid;
            int ixj = i ^ j;
            if (ixj > i) {
                float vi = sv[i], vj = sv[ixj];
                int ii = si[i], ij = si[ixj];
                bool b_ji = (vj > vi) || (vj == vi && ij < ii);
                bool up = ((i & ksz) == 0);
                if (up ? b_ji : !b_ji) {
                    sv[i] = vj; sv[ixj] = vi;
                    si[i] = ij; si[ixj] = ii;
                }
            }
            __syncthreads();
        }
    }

    for (int t = tid; t < KK * TOTAL; t += 512) {
        int k = t / TOTAL, d = t - k * TOTAL;
        if (d < 96) {
            int n = g * NPER + si[k];
            pooled[k][d] = hcat[n * 96 + d];
        } else {
            pooled[k][96] = sv[k];
        }
    }
    __syncthreads();

    for (int t = tid; t < C1C * KK; t += 512) {
        int o = t / KK, k = t - o * KK;
        float s = cb1[o];
        for (int d = 0; d < TOTAL; ++d) s += cw1[o * TOTAL + d] * pooled[k][d];
        c1b[o][k] = fmaxf(s, 0.f);
    }
    __syncthreads();

    for (int t = tid; t < C1C * POOL_LEN; t += 512) {
        int o = t / POOL_LEN, x = t - o * POOL_LEN;
        p1[o][x] = fmaxf(c1b[o][2 * x], c1b[o][2 * x + 1]);
    }
    __syncthreads();

    for (int t = tid; t < C2C * CONV_OUT; t += 512) {
        int o = t / CONV_OUT, x = t - o * CONV_OUT;
        float s = cb2[o];
        for (int i = 0; i < C1C; ++i) {
            #pragma unroll
            for (int j = 0; j < KW2C; ++j)
                s += cw2[(o * C1C + i) * KW2C + j] * p1[i][x + j];
        }
        flat[o * CONV_OUT + x] = fmaxf(s, 0.f);
    }
    __syncthreads();

    for (int m = tid; m < OUTD; m += 512) {
        float s = ob[m];
        for (int d = 0; d < DENSE; ++d) s += flat[d] * ow[d * OUTD + m];
        out[g * OUTD + m] = fmaxf(s, 0.f);
    }
}

extern "C" void kernel_launch(void* const* d_in, const int* in_sizes, int n_in,
                              void* d_out, int out_size, void* d_ws, size_t ws_size,
                              hipStream_t stream) {
    const float* node_feat = (const float*)d_in[0];
    const float* edge_feat = (const float*)d_in[1];
    const int*   edge_src  = (const int*)  d_in[2];
    const int*   edge_dst  = (const int*)  d_in[3];
    const float* W0 = (const float*)d_in[4];
    const float* b0 = (const float*)d_in[5];
    const float* W1 = (const float*)d_in[6];
    const float* b1 = (const float*)d_in[7];
    const float* W2 = (const float*)d_in[8];
    const float* b2 = (const float*)d_in[9];
    const float* W3 = (const float*)d_in[10];
    const float* b3 = (const float*)d_in[11];
    const float* cw1 = (const float*)d_in[12];
    const float* cb1 = (const float*)d_in[13];
    const float* cw2 = (const float*)d_in[14];
    const float* cb2 = (const float*)d_in[15];
    const float* ow  = (const float*)d_in[16];
    const float* ob  = (const float*)d_in[17];
    float* outp = (float*)d_out;

    // ---- workspace layout (bedges aliases hcat: bedges dead before hcat's first write) ----
    float* ws   = (float*)d_ws;
    float* hcat = ws;                         // N*96 floats (24 MB)
    u64*   bedges = (u64*)ws;                 // E u64 (8 MB) -- alias, consumed by k_csr before k_layer writes hcat
    float* y    = hcat + (size_t)NN * 96;     // N*32
    float* z    = y + NN * 32;                // N*32  (alias e2n)
    float* y3   = z + NN * 32;                // N
    float* z3v  = y3 + NN;                    // N
    float* degf = z3v + NN;                   // N
    int* rowptr = (int*)(degf + NN);          // N+1
    int* s_src  = rowptr + NN + 1;            // E
    int* s_eid  = s_src + EE;                 // E
    int* bhist  = s_eid + EE;                 // 256
    int* bbase  = bhist + 256;                // 257
    int* bcur   = bbase + 257;                // 256
    float* e2n  = z;                          // alias

    hipMemsetAsync(bhist, 0, 256 * sizeof(int), stream);

    // CSR build (bucketed, write-coalesced)
    k_bhist<<<EE / 4096, 256, 0, stream>>>(edge_dst, bhist);
    k_bscan<<<1, 256, 0, stream>>>(bhist, bbase, bcur);
    k_bucket<<<EE / 4096, 256, 0, stream>>>(edge_src, edge_dst, bcur, bedges);
    k_csr<<<256, 256, 0, stream>>>(bedges, bbase, rowptr, degf, s_src, s_eid);

    // e2n gather + layer0
    k_e2n<<<NN * 8 / 256, 256, 0, stream>>>(edge_feat, rowptr, s_eid, e2n);
    k_layer0<<<NN * 32 / 256, 256, 0, stream>>>(node_feat, e2n, W0, y);
    k_gather32<<<NN * 8 / 256, 256, 0, stream>>>(rowptr, s_src, y, b0, z);

    k_layer<<<NN / 64, 256, 0, stream>>>(z, degf, W1, hcat, 0, y);
    k_gather32<<<NN * 8 / 256, 256, 0, stream>>>(rowptr, s_src, y, b1, z);

    k_layer<<<NN / 64, 256, 0, stream>>>(z, degf, W2, hcat, 32, y);
    k_gather32<<<NN * 8 / 256, 256, 0, stream>>>(rowptr, s_src, y, b2, z);

    k_layer3<<<NN / 64, 256, 0, stream>>>(z, degf, W3, hcat, y3);
    k_gather1<<<NN / 256, 256, 0, stream>>>(rowptr, s_src, y3, b3, z3v);

    k_head<<<GG, 512, 0, stream>>>(z3v, degf, hcat, cw1, cb1, cw2, cb2, ow, ob, outp);
}

// Round 4
// 455.373 us; speedup vs baseline: 1.8491x; 1.0772x over previous
//
#include <hip/hip_runtime.h>
#include <math.h>

#define GG 128
#define NPER 512
#define KK 30
#define NN (GG*NPER)        // 65536
#define EE 1048576
#define DIN0 96
#define DL 32
#define TOTAL 97
#define C1C 16
#define C2C 32
#define KW2C 5
#define POOL_LEN 15
#define CONV_OUT 11
#define DENSE 352
#define OUTD 128
#define PB_CAP 6144

typedef unsigned long long u64;

// ================= P0: coarse bucket histogram (bucket = dst>>8) =================
__global__ __launch_bounds__(256) void k_bhist(const int* __restrict__ dst, int* __restrict__ bhist) {
    __shared__ int h[256];
    int t = threadIdx.x;
    h[t] = 0;
    __syncthreads();
    int base = blockIdx.x * 4096;
    for (int i = t; i < 4096; i += 256) atomicAdd(&h[dst[base + i] >> 8], 1);
    __syncthreads();
    atomicAdd(&bhist[t], h[t]);
}

__global__ __launch_bounds__(256) void k_bscan(const int* __restrict__ bhist,
                                               int* __restrict__ bbase, int* __restrict__ bcur) {
    __shared__ int sc[2][256];
    int t = threadIdx.x;
    int v0 = bhist[t];
    sc[0][t] = v0;
    __syncthreads();
    int c = 0;
    for (int off = 1; off < 256; off <<= 1) {
        int v = sc[c][t];
        if (t >= off) v += sc[c][t - off];
        sc[c ^ 1][t] = v;
        __syncthreads();
        c ^= 1;
    }
    int incl = sc[c][t];
    bbase[t] = incl - v0;
    bcur[t]  = incl - v0;
    if (t == 255) bbase[256] = incl;
}

// packed: bkt(8b)<<44 | eid(20b)<<24 | src(16b)<<8 | dstloc(8b)
__global__ __launch_bounds__(256) void k_bucket(const int* __restrict__ src, const int* __restrict__ dst,
                                                int* __restrict__ bcur, u64* __restrict__ bedges) {
    __shared__ u64 stage[4096];
    __shared__ int hist[256], sc[2][256], excl[256], cur[256], runbase[256];
    int t = threadIdx.x;
    hist[t] = 0; cur[t] = 0;
    __syncthreads();
    int base = blockIdx.x * 4096;
    u64 r[16];
    #pragma unroll
    for (int i = 0; i < 16; ++i) {
        int e = base + t + i * 256;
        int d = dst[e], s = src[e];
        int bkt = d >> 8;
        r[i] = ((u64)bkt << 44) | ((u64)e << 24) | ((u64)s << 8) | (u64)(d & 255);
        atomicAdd(&hist[bkt], 1);
    }
    __syncthreads();
    sc[0][t] = hist[t];
    __syncthreads();
    int c = 0;
    for (int off = 1; off < 256; off <<= 1) {
        int v = sc[c][t];
        if (t >= off) v += sc[c][t - off];
        sc[c ^ 1][t] = v;
        __syncthreads();
        c ^= 1;
    }
    excl[t] = sc[c][t] - hist[t];
    runbase[t] = atomicAdd(&bcur[t], hist[t]);
    __syncthreads();
    #pragma unroll
    for (int i = 0; i < 16; ++i) {
        int bkt = (int)(r[i] >> 44);
        int li = excl[bkt] + atomicAdd(&cur[bkt], 1);
        stage[li] = r[i];
    }
    __syncthreads();
    for (int idx = t; idx < 4096; idx += 256) {
        u64 p = stage[idx];
        int bkt = (int)(p >> 44);
        bedges[runbase[bkt] + (idx - excl[bkt])] = p;
    }
}

__global__ __launch_bounds__(256) void k_csr(const u64* __restrict__ bedges, const int* __restrict__ bbase,
                                             int* __restrict__ rowptr, float* __restrict__ degf,
                                             int* __restrict__ s_src, int* __restrict__ s_eid) {
    __shared__ u64 stage[PB_CAP];
    __shared__ int hist[256], sc[2][256], excl[256], cur[256];
    int t = threadIdx.x, b = blockIdx.x;
    hist[t] = 0; cur[t] = 0;
    __syncthreads();
    int beg = bbase[b], end = bbase[b + 1];
    int cnt = end - beg;
    for (int j = t; j < cnt; j += 256) {
        u64 p = bedges[beg + j];
        if (j < PB_CAP) stage[j] = p;
        atomicAdd(&hist[(int)(p & 255)], 1);
    }
    __syncthreads();
    sc[0][t] = hist[t];
    __syncthreads();
    int c = 0;
    for (int off = 1; off < 256; off <<= 1) {
        int v = sc[c][t];
        if (t >= off) v += sc[c][t - off];
        sc[c ^ 1][t] = v;
        __syncthreads();
        c ^= 1;
    }
    excl[t] = sc[c][t] - hist[t];
    int n = b * 256 + t;
    rowptr[n] = beg + excl[t];
    degf[n] = (float)hist[t] + 1.0f;
    if (b == 255 && t == 255) rowptr[NN] = EE;
    __syncthreads();
    int lim = cnt < PB_CAP ? cnt : PB_CAP;
    for (int j = t; j < lim; j += 256) {
        u64 p = stage[j];
        int dl = (int)(p & 255);
        int pos = beg + excl[dl] + atomicAdd(&cur[dl], 1);
        s_src[pos] = (int)((p >> 8) & 0xFFFF);
        s_eid[pos] = (int)((p >> 24) & 0xFFFFF);
    }
    for (int j = PB_CAP + t; j < cnt; j += 256) {
        u64 p = bedges[beg + j];
        int dl = (int)(p & 255);
        int pos = beg + excl[dl] + atomicAdd(&cur[dl], 1);
        s_src[pos] = (int)((p >> 8) & 0xFFFF);
        s_eid[pos] = (int)((p >> 24) & 0xFFFFF);
    }
}

// ================= e2n gather =================
__global__ __launch_bounds__(256) void k_e2n(const float* __restrict__ edge_feat,
                                             const int* __restrict__ rowptr,
                                             const int* __restrict__ s_eid,
                                             float* __restrict__ e2n) {
    int t = blockIdx.x * 256 + threadIdx.x;
    int n = t >> 3, l = t & 7;
    int beg = rowptr[n], end = rowptr[n + 1];
    const float4* ef4 = (const float4*)edge_feat;
    float4 s = make_float4(0.f, 0.f, 0.f, 0.f);
    for (int j = beg; j < end; ++j) {
        int e = s_eid[j];
        float4 v = ef4[e * 8 + l];
        s.x += v.x; s.y += v.y; s.z += v.z; s.w += v.w;
    }
    ((float4*)e2n)[n * 8 + l] = s;
}

// ================= layer0: y0 = [node_feat | e2n] @ W0 =================
__global__ __launch_bounds__(256) void k_layer0(const float* __restrict__ node_feat,
                                                const float* __restrict__ e2n,
                                                const float* __restrict__ W0,
                                                float* __restrict__ y) {
    __shared__ float Wl[DIN0 * DL];
    for (int i = threadIdx.x; i < DIN0 * DL; i += 256) Wl[i] = W0[i];
    __syncthreads();
    int t = blockIdx.x * 256 + threadIdx.x;
    int n = t >> 5, c = t & 31;
    const float* nf = node_feat + n * 64;
    const float* ef = e2n + n * 32;
    float s = 0.f;
    #pragma unroll
    for (int k = 0; k < 64; ++k) s += nf[k] * Wl[k * 32 + c];
    #pragma unroll
    for (int k = 0; k < 32; ++k) s += ef[k] * Wl[(64 + k) * 32 + c];
    y[t] = s;
}

// ================= fused gather + tanh + hcat + next-layer matmul =================
// thread (nl = t>>3, l = t&7): gathers float4 of z, tanh -> h (own hcat float4),
// stages h in LDS, then computes yout float4 for the same (n, l*4..l*4+3).
__global__ __launch_bounds__(256) void k_gl(const int* __restrict__ rowptr,
                                            const int* __restrict__ s_src,
                                            const float* __restrict__ degf,
                                            const float* __restrict__ yin,
                                            const float* __restrict__ bprev,
                                            const float* __restrict__ W,     // 32x32 (next layer)
                                            float* __restrict__ hcat, int colbase,
                                            float* __restrict__ yout) {
    __shared__ float Wl[DL * DL];
    __shared__ float hb[32 * 33];
    for (int i = threadIdx.x; i < DL * DL; i += 256) Wl[i] = W[i];
    int t = threadIdx.x;
    int nl = t >> 3, l = t & 7;
    int n = blockIdx.x * 32 + nl;
    int beg = rowptr[n], end = rowptr[n + 1];
    const float4* y4 = (const float4*)yin;
    float4 bb = ((const float4*)bprev)[l];
    float4 s = y4[n * 8 + l];
    s.x += bb.x; s.y += bb.y; s.z += bb.z; s.w += bb.w;
    for (int j = beg; j < end; ++j) {
        float4 v = y4[s_src[j] * 8 + l];
        s.x += v.x; s.y += v.y; s.z += v.z; s.w += v.w;
    }
    float dg = degf[n];
    float4 h;
    h.x = tanhf(s.x / dg); h.y = tanhf(s.y / dg); h.z = tanhf(s.z / dg); h.w = tanhf(s.w / dg);
    *(float4*)&hcat[n * 96 + colbase + l * 4] = h;
    hb[nl * 33 + l * 4 + 0] = h.x;
    hb[nl * 33 + l * 4 + 1] = h.y;
    hb[nl * 33 + l * 4 + 2] = h.z;
    hb[nl * 33 + l * 4 + 3] = h.w;
    __syncthreads();
    float4 o = make_float4(0.f, 0.f, 0.f, 0.f);
    #pragma unroll
    for (int k = 0; k < 32; ++k) {
        float hv = hb[nl * 33 + k];
        o.x += hv * Wl[k * 32 + l * 4 + 0];
        o.y += hv * Wl[k * 32 + l * 4 + 1];
        o.z += hv * Wl[k * 32 + l * 4 + 2];
        o.w += hv * Wl[k * 32 + l * 4 + 3];
    }
    ((float4*)yout)[n * 8 + l] = o;
}

// variant: last 32-wide layer -> hcat cols 64..95 + scalar y3 = h @ W3
__global__ __launch_bounds__(256) void k_gl3(const int* __restrict__ rowptr,
                                             const int* __restrict__ s_src,
                                             const float* __restrict__ degf,
                                             const float* __restrict__ yin,
                                             const float* __restrict__ bprev,
                                             const float* __restrict__ W3,    // 32x1
                                             float* __restrict__ hcat,
                                             float* __restrict__ y3) {
    __shared__ float W3l[32];
    __shared__ float hb[32 * 33];
    if (threadIdx.x < 32) W3l[threadIdx.x] = W3[threadIdx.x];
    int t = threadIdx.x;
    int nl = t >> 3, l = t & 7;
    int n = blockIdx.x * 32 + nl;
    int beg = rowptr[n], end = rowptr[n + 1];
    const float4* y4 = (const float4*)yin;
    float4 bb = ((const float4*)bprev)[l];
    float4 s = y4[n * 8 + l];
    s.x += bb.x; s.y += bb.y; s.z += bb.z; s.w += bb.w;
    for (int j = beg; j < end; ++j) {
        float4 v = y4[s_src[j] * 8 + l];
        s.x += v.x; s.y += v.y; s.z += v.z; s.w += v.w;
    }
    float dg = degf[n];
    float4 h;
    h.x = tanhf(s.x / dg); h.y = tanhf(s.y / dg); h.z = tanhf(s.z / dg); h.w = tanhf(s.w / dg);
    *(float4*)&hcat[n * 96 + 64 + l * 4] = h;
    hb[nl * 33 + l * 4 + 0] = h.x;
    hb[nl * 33 + l * 4 + 1] = h.y;
    hb[nl * 33 + l * 4 + 2] = h.z;
    hb[nl * 33 + l * 4 + 3] = h.w;
    __syncthreads();
    if (t < 32) {
        float s3 = 0.f;
        #pragma unroll
        for (int k = 0; k < 32; ++k) s3 += hb[t * 33 + k] * W3l[k];
        y3[blockIdx.x * 32 + t] = s3;
    }
}

__global__ __launch_bounds__(256) void k_gather1(const int* __restrict__ rowptr,
                                                 const int* __restrict__ s_src,
                                                 const float* __restrict__ y3,
                                                 const float* __restrict__ b3,
                                                 float* __restrict__ z3) {
    int n = blockIdx.x * 256 + threadIdx.x;
    if (n < NN) {
        int beg = rowptr[n], end = rowptr[n + 1];
        float s = y3[n] + b3[0];
        for (int j = beg; j < end; ++j) s += y3[s_src[j]];
        z3[n] = s;
    }
}

// ================= head =================
__global__ __launch_bounds__(512) void k_head(const float* __restrict__ z3,
                                              const float* __restrict__ degf,
                                              const float* __restrict__ hcat,
                                              const float* __restrict__ cw1, const float* __restrict__ cb1,
                                              const float* __restrict__ cw2, const float* __restrict__ cb2,
                                              const float* __restrict__ ow,  const float* __restrict__ ob,
                                              float* __restrict__ out) {
    __shared__ float sv[NPER];
    __shared__ int   si[NPER];
    __shared__ float pooled[KK][TOTAL];
    __shared__ float c1b[C1C][KK];
    __shared__ float p1[C1C][POOL_LEN];
    __shared__ float flat[DENSE];
    int g = blockIdx.x;
    int tid = threadIdx.x;

    {
        int n = g * NPER + tid;
        sv[tid] = tanhf(z3[n] / degf[n]);
        si[tid] = tid;
    }
    __syncthreads();

    for (int ksz = 2; ksz <= NPER; ksz <<= 1) {
        for (int j = ksz >> 1; j > 0; j >>= 1) {
            int i = tid;
            int ixj = i ^ j;
            if (ixj > i) {
                float vi = sv[i], vj = sv[ixj];
                int ii = si[i], ij = si[ixj];
                bool b_ji = (vj > vi) || (vj == vi && ij < ii);
                bool up = ((i & ksz) == 0);
                if (up ? b_ji : !b_ji) {
                    sv[i] = vj; sv[ixj] = vi;
                    si[i] = ij; si[ixj] = ii;
                }
            }
            __syncthreads();
        }
    }

    for (int t = tid; t < KK * TOTAL; t += 512) {
        int k = t / TOTAL, d = t - k * TOTAL;
        if (d < 96) {
            int n = g * NPER + si[k];
            pooled[k][d] = hcat[n * 96 + d];
        } else {
            pooled[k][96] = sv[k];
        }
    }
    __syncthreads();

    for (int t = tid; t < C1C * KK; t += 512) {
        int o = t / KK, k = t - o * KK;
        float s = cb1[o];
        for (int d = 0; d < TOTAL; ++d) s += cw1[o * TOTAL + d] * pooled[k][d];
        c1b[o][k] = fmaxf(s, 0.f);
    }
    __syncthreads();

    for (int t = tid; t < C1C * POOL_LEN; t += 512) {
        int o = t / POOL_LEN, x = t - o * POOL_LEN;
        p1[o][x] = fmaxf(c1b[o][2 * x], c1b[o][2 * x + 1]);
    }
    __syncthreads();

    for (int t = tid; t < C2C * CONV_OUT; t += 512) {
        int o = t / CONV_OUT, x = t - o * CONV_OUT;
        float s = cb2[o];
        for (int i = 0; i < C1C; ++i) {
            #pragma unroll
            for (int j = 0; j < KW2C; ++j)
                s += cw2[(o * C1C + i) * KW2C + j] * p1[i][x + j];
        }
        flat[o * CONV_OUT + x] = fmaxf(s, 0.f);
    }
    __syncthreads();

    for (int m = tid; m < OUTD; m += 512) {
        float s = ob[m];
        for (int d = 0; d < DENSE; ++d) s += flat[d] * ow[d * OUTD + m];
        out[g * OUTD + m] = fmaxf(s, 0.f);
    }
}

extern "C" void kernel_launch(void* const* d_in, const int* in_sizes, int n_in,
                              void* d_out, int out_size, void* d_ws, size_t ws_size,
                              hipStream_t stream) {
    const float* node_feat = (const float*)d_in[0];
    const float* edge_feat = (const float*)d_in[1];
    const int*   edge_src  = (const int*)  d_in[2];
    const int*   edge_dst  = (const int*)  d_in[3];
    const float* W0 = (const float*)d_in[4];
    const float* b0 = (const float*)d_in[5];
    const float* W1 = (const float*)d_in[6];
    const float* b1 = (const float*)d_in[7];
    const float* W2 = (const float*)d_in[8];
    const float* b2 = (const float*)d_in[9];
    const float* W3 = (const float*)d_in[10];
    const float* b3 = (const float*)d_in[11];
    const float* cw1 = (const float*)d_in[12];
    const float* cb1 = (const float*)d_in[13];
    const float* cw2 = (const float*)d_in[14];
    const float* cb2 = (const float*)d_in[15];
    const float* ow  = (const float*)d_in[16];
    const float* ob  = (const float*)d_in[17];
    float* outp = (float*)d_out;

    // ---- workspace layout (bedges aliases hcat: consumed by k_csr before hcat's first write) ----
    float* ws   = (float*)d_ws;
    float* hcat = ws;                         // N*96
    u64*   bedges = (u64*)ws;                 // E u64 (alias)
    float* yA   = hcat + (size_t)NN * 96;     // N*32
    float* yB   = yA + NN * 32;               // N*32  (alias e2n)
    float* y3   = yB + NN * 32;               // N
    float* z3v  = y3 + NN;                    // N
    float* degf = z3v + NN;                   // N
    int* rowptr = (int*)(degf + NN);          // N+1
    int* s_src  = rowptr + NN + 1;            // E
    int* s_eid  = s_src + EE;                 // E
    int* bhist  = s_eid + EE;                 // 256
    int* bbase  = bhist + 256;                // 257
    int* bcur   = bbase + 257;                // 256
    float* e2n  = yB;                         // alias (consumed by layer0 before gl1 writes yB? no: layer0 writes yA, gl1 reads yA writes yB -- e2n dead by then)

    hipMemsetAsync(bhist, 0, 256 * sizeof(int), stream);

    k_bhist<<<EE / 4096, 256, 0, stream>>>(edge_dst, bhist);
    k_bscan<<<1, 256, 0, stream>>>(bhist, bbase, bcur);
    k_bucket<<<EE / 4096, 256, 0, stream>>>(edge_src, edge_dst, bcur, bedges);
    k_csr<<<256, 256, 0, stream>>>(bedges, bbase, rowptr, degf, s_src, s_eid);

    k_e2n<<<NN * 8 / 256, 256, 0, stream>>>(edge_feat, rowptr, s_eid, e2n);
    k_layer0<<<NN * 32 / 256, 256, 0, stream>>>(node_feat, e2n, W0, yA);

    // round 1: gather yA (+b0), tanh -> hcat[0..31], matmul W1 -> yB
    k_gl<<<NN / 32, 256, 0, stream>>>(rowptr, s_src, degf, yA, b0, W1, hcat, 0, yB);
    // round 2: gather yB (+b1), tanh -> hcat[32..63], matmul W2 -> yA
    k_gl<<<NN / 32, 256, 0, stream>>>(rowptr, s_src, degf, yB, b1, W2, hcat, 32, yA);
    // round 3: gather yA (+b2), tanh -> hcat[64..95], y3 = h @ W3
    k_gl3<<<NN / 32, 256, 0, stream>>>(rowptr, s_src, degf, yA, b2, W3, hcat, y3);
    // round 4 (scalar)
    k_gather1<<<NN / 256, 256, 0, stream>>>(rowptr, s_src, y3, b3, z3v);

    k_head<<<GG, 512, 0, stream>>>(z3v, degf, hcat, cw1, cb1, cw2, cb2, ow, ob, outp);
}